// Round 3
// baseline (155.726 us; speedup 1.0000x reference)
//
#include <hip/hip_runtime.h>
#include <stdint.h>

#define NPIX 9216   // 96*96
#define NIMG 32

// ---------- JAX threefry2x32 (20 rounds), bit-exact ----------
__device__ __forceinline__ uint32_t rotl32(uint32_t x, int d){ return (x<<d)|(x>>(32-d)); }

__device__ __forceinline__ void threefry(uint32_t k0, uint32_t k1, uint32_t x0, uint32_t x1,
                                         uint32_t &o0, uint32_t &o1){
  uint32_t ks2 = k0 ^ k1 ^ 0x1BD11BDAu;
  x0 += k0; x1 += k1;
  x0+=x1; x1=rotl32(x1,13); x1^=x0;
  x0+=x1; x1=rotl32(x1,15); x1^=x0;
  x0+=x1; x1=rotl32(x1,26); x1^=x0;
  x0+=x1; x1=rotl32(x1,6);  x1^=x0;
  x0+=k1; x1+=ks2+1u;
  x0+=x1; x1=rotl32(x1,17); x1^=x0;
  x0+=x1; x1=rotl32(x1,29); x1^=x0;
  x0+=x1; x1=rotl32(x1,16); x1^=x0;
  x0+=x1; x1=rotl32(x1,24); x1^=x0;
  x0+=ks2; x1+=k0+2u;
  x0+=x1; x1=rotl32(x1,13); x1^=x0;
  x0+=x1; x1=rotl32(x1,15); x1^=x0;
  x0+=x1; x1=rotl32(x1,26); x1^=x0;
  x0+=x1; x1=rotl32(x1,6);  x1^=x0;
  x0+=k0; x1+=k1+3u;
  x0+=x1; x1=rotl32(x1,17); x1^=x0;
  x0+=x1; x1=rotl32(x1,29); x1^=x0;
  x0+=x1; x1=rotl32(x1,16); x1^=x0;
  x0+=x1; x1=rotl32(x1,24); x1^=x0;
  x0+=k1; x1+=ks2+4u;
  x0+=x1; x1=rotl32(x1,13); x1^=x0;
  x0+=x1; x1=rotl32(x1,15); x1^=x0;
  x0+=x1; x1=rotl32(x1,26); x1^=x0;
  x0+=x1; x1=rotl32(x1,6);  x1^=x0;
  x0+=ks2; x1+=k0+5u;
  o0=x0; o1=x1;
}

__device__ __forceinline__ float clip01_div255(float x){
  return fminf(fmaxf(x/255.0f, 0.0f), 1.0f);
}

// ---------- Kernel 1: fused max + fg-mask + threefry top-50 (both classes) + stats ----
// One block per image.
__global__ __launch_bounds__(256) void kprep(const float* __restrict__ in,
                                             float* __restrict__ train_s,
                                             float* __restrict__ meanstd){
#pragma clang fp contract(off)
  int img = blockIdx.x;
  int tid = threadIdx.x;

  __shared__ uint32_t score[NPIX];       // 36 KB
  __shared__ uint32_t fgbits[NPIX/32];   // 1152 B, fg mask cached between classes
  __shared__ uint64_t cand[1024];        // 8 KB
  __shared__ int hist[129];
  __shared__ int ncand, bbin;
  __shared__ float red[3][4];
  __shared__ int   tIdx[100];
  __shared__ float feat[100][5];
  __shared__ float mv[5], sv[5];

  const float* p = in + (size_t)img*NPIX*3;

  // ---- channel max (fmax exact & associative -> identical to any reduction order)
  float m0=0.f, m1=0.f, m2=0.f;
  for(int i=tid;i<NPIX;i+=256){
    m0=fmaxf(m0, clip01_div255(p[i*3+0]));
    m1=fmaxf(m1, clip01_div255(p[i*3+1]));
    m2=fmaxf(m2, clip01_div255(p[i*3+2]));
  }
  for(int off=32;off>0;off>>=1){
    m0=fmaxf(m0,__shfl_down(m0,off));
    m1=fmaxf(m1,__shfl_down(m1,off));
    m2=fmaxf(m2,__shfl_down(m2,off));
  }
  int lane = tid & 63, wv = tid >> 6;
  if(lane==0){ red[0][wv]=m0; red[1][wv]=m1; red[2][wv]=m2; }
  __syncthreads();
  float c0=fmaxf(fmaxf(red[0][0],red[0][1]),fmaxf(red[0][2],red[0][3]));
  float c1=fmaxf(fmaxf(red[1][0],red[1][1]),fmaxf(red[1][2],red[1][3]));
  float c2=fmaxf(fmaxf(red[2][0],red[2][1]),fmaxf(red[2][2],red[2][3]));

  // ---- split keys (partitionable threefry, verified bit-exact rounds 1-2)
  uint32_t ik0, ik1; threefry(0u, 42u, 0u, (uint32_t)img, ik0, ik1);

  for(int cls=0; cls<2; cls++){
    if(tid<129) hist[tid]=0;
    if(tid==0)  ncand=0;
    __syncthreads();

    uint32_t s0, s1; threefry(ik0, ik1, 0u, (uint32_t)cls, s0, s1);

    for(int i=tid;i<NPIX;i+=256){
      bool valid;
      if(cls==0){
        float a=clip01_div255(p[i*3+0])/c0;
        float b=clip01_div255(p[i*3+1])/c1;
        float c=clip01_div255(p[i*3+2])/c2;
        bool fg = (a>0.f && a<0.6f) || (b>0.f && b<0.6f) || (c>0.f && c<0.6f);
        // cache fg bits: wave lanes cover 64 consecutive i -> 2 words
        uint64_t bal = __ballot(fg);
        if(lane==0){
          int w = i >> 5;               // i = base of lane0, 32-aligned
          fgbits[w]   = (uint32_t)bal;
          fgbits[w+1] = (uint32_t)(bal>>32);
        }
        valid = fg;
      } else {
        valid = !((fgbits[i>>5] >> (i&31)) & 1u);
      }
      uint32_t b1,b2; threefry(s0, s1, 0u, (uint32_t)i, b1, b2);
      uint32_t vv = valid ? ((b1 ^ b2) >> 9) + 1u : 0u;   // monotone in uniform; 0 = invalid
      score[i] = vv;
      atomicAdd(&hist[vv>>16], 1);
    }
    __syncthreads();

    if(tid==0){
      int acc=0, b=128;
      for(; b>=0; b--){ acc += hist[b]; if(acc>=50) break; }
      bbin = b;
    }
    __syncthreads();

    int bb = bbin;
    for(int i=tid;i<NPIX;i+=256){
      uint32_t vv = score[i];
      if((int)(vv>>16) >= bb){
        int pos = atomicAdd(&ncand,1);
        if(pos < 1024)
          cand[pos] = ((uint64_t)vv << 14) | (uint64_t)(16383 - i);  // higher key = earlier
      }
    }
    __syncthreads();

    int m = ncand; if(m>1024) m=1024;
    for(int c=tid;c<m;c+=256){
      uint64_t k = cand[c];
      int r = 0;
      for(int j=0;j<m;j++) r += (cand[j] > k);
      if(r < 50) tIdx[cls*50+r] = 16383 - (int)(k & 16383u);
    }
    __syncthreads();
  }

  // ---- stats (bit-identical to round-1/2 kstats)
  if(tid<100){
    int pp = tIdx[tid];
    int i=pp/96, j=pp-i*96;
    const float* px = p + (size_t)pp*3;
    for(int c=0;c<3;c++){
      float ip=clip01_div255(px[c]);
      feat[tid][c]=ip/255.0f;
    }
    feat[tid][3]=((float)i/96.0f)*100.0f;
    feat[tid][4]=((float)j/96.0f)*100.0f;
  }
  __syncthreads();
  if(tid<5){
    float s=0.f;
    for(int r=0;r<100;r++) s=s+feat[r][tid];
    float m=s/100.0f;
    mv[tid]=m;
    float v=0.f;
    for(int r=0;r<100;r++){ float d=feat[r][tid]-m; float q=d*d; v=v+q; }
    sv[tid]=sqrtf(v/100.0f);
  }
  __syncthreads();
  if(tid<100){
    for(int k=0;k<5;k++) train_s[(img*100+tid)*5+k]=(feat[tid][k]-mv[k])/sv[k];
  }
  if(tid<5)       meanstd[img*10+tid]=mv[tid];
  else if(tid<10) meanstd[img*10+tid]=sv[tid-5];
}

// ---------- Kernel 2: brute-force 5-NN, fg/bg phase split, scalar train loads ----
__global__ __launch_bounds__(128) void kknn(const float* __restrict__ in,
                                            const float* __restrict__ train_s,
                                            const float* __restrict__ meanstd,
                                            float* __restrict__ out){
#pragma clang fp contract(off)
  int img   = blockIdx.x / 72;
  int chunk = blockIdx.x % 72;
  int tid   = threadIdx.x;
  __shared__ float pix[384];

  // coalesced staging load of this chunk's 384 contiguous dwords
  const float* cb = in + ((size_t)img*NPIX + (size_t)chunk*128)*3;
  pix[tid]     = cb[tid];
  pix[tid+128] = cb[tid+128];
  pix[tid+256] = cb[tid+256];

  const float* ms = meanstd + img*10;     // wave-uniform -> scalar loads
  const float* tg = train_s + img*500;    // wave-uniform -> scalar loads
  __syncthreads();

  int p = chunk*128+tid;
  int i=p/96, j=p-i*96;
  float ip0=clip01_div255(pix[tid*3+0]);
  float ip1=clip01_div255(pix[tid*3+1]);
  float ip2=clip01_div255(pix[tid*3+2]);
  float tt[5];
  {
    float f[5]={ip0/255.0f, ip1/255.0f, ip2/255.0f,
                ((float)i/96.0f)*100.0f, ((float)j/96.0f)*100.0f};
#pragma unroll
    for(int k=0;k<5;k++) tt[k]=(f[k]-ms[k])/ms[5+k];
  }

  float bd0=1e30f,bd1=1e30f,bd2=1e30f,bd3=1e30f,bd4=1e30f;

  // ---- phase A: fg neighbors 0..49 (all label 1) — no identity tracking needed
#pragma unroll 5
  for(int jn=0;jn<50;jn++){
    float s=0.f;
#pragma unroll
    for(int k=0;k<5;k++){ float df=tt[k]-tg[jn*5+k]; float q=df*df; s=s+q; }
    float d=sqrtf(s);
    bool l4=d<bd4, l3=d<bd3, l2=d<bd2, l1=d<bd1, l0=d<bd0;
    bd4 = l4 ? (l3?bd3:d) : bd4;
    bd3 = l3 ? (l2?bd2:d) : bd3;
    bd2 = l2 ? (l1?bd1:d) : bd2;
    bd1 = l1 ? (l0?bd0:d) : bd1;
    bd0 = l0 ? d : bd0;
  }

  // ---- phase B: bg neighbors 50..99 (label 0); existing entries all label 1
  int bx0=1,bx1=1,bx2=1,bx3=1,bx4=1;
#pragma unroll 5
  for(int jn=50;jn<100;jn++){
    float s=0.f;
#pragma unroll
    for(int k=0;k<5;k++){ float df=tt[k]-tg[jn*5+k]; float q=df*df; s=s+q; }
    float d=sqrtf(s);
    // strict-< insert: on tie, existing (earlier train index) stays -> stable top_k
    bool l4=d<bd4, l3=d<bd3, l2=d<bd2, l1=d<bd1, l0=d<bd0;
    bd4 = l4 ? (l3?bd3:d) : bd4;   bx4 = l4 ? (l3?bx3:0) : bx4;
    bd3 = l3 ? (l2?bd2:d) : bd3;   bx3 = l3 ? (l2?bx2:0) : bx3;
    bd2 = l2 ? (l1?bd1:d) : bd2;   bx2 = l2 ? (l1?bx1:0) : bx2;
    bd1 = l1 ? (l0?bd0:d) : bd1;   bx1 = l1 ? (l0?bx0:0) : bx1;
    bd0 = l0 ? d : bd0;            bx0 = l0 ? 0 : bx0;
  }

  int cnt = bx0+bx1+bx2+bx3+bx4;
  bool seg = cnt>=2;                  // mean>=0.3  <=>  count>=2
  __syncthreads();                    // pix[] reuse fence
  pix[tid*3+0]=seg?ip0:0.f;
  pix[tid*3+1]=seg?ip1:0.f;
  pix[tid*3+2]=seg?ip2:0.f;
  __syncthreads();
  float* ob = out + ((size_t)img*NPIX + (size_t)chunk*128)*3;
  ob[tid]     = pix[tid];
  ob[tid+128] = pix[tid+128];
  ob[tid+256] = pix[tid+256];
}

extern "C" void kernel_launch(void* const* d_in, const int* in_sizes, int n_in,
                              void* d_out, int out_size, void* d_ws, size_t ws_size,
                              hipStream_t stream) {
  const float* in = (const float*)d_in[0];
  float* out = (float*)d_out;
  float* train_s = (float*)d_ws;                       // 32*500*4 = 64000 B
  float* meanstd = (float*)((char*)d_ws + 64000);      // 32*10*4  = 1280 B

  kprep<<<NIMG,    256, 0, stream>>>(in, train_s, meanstd);
  kknn <<<NIMG*72, 128, 0, stream>>>(in, train_s, meanstd, out);
}

// Round 4
// 132.892 us; speedup vs baseline: 1.1718x; 1.1718x over previous
//
#include <hip/hip_runtime.h>
#include <stdint.h>

#define NPIX 9216   // 96*96
#define NIMG 32
#define FLAG_MAGIC 0x5EED5EED

// ---------- JAX threefry2x32 (20 rounds), bit-exact ----------
__device__ __forceinline__ uint32_t rotl32(uint32_t x, int d){ return (x<<d)|(x>>(32-d)); }

__device__ __forceinline__ void threefry(uint32_t k0, uint32_t k1, uint32_t x0, uint32_t x1,
                                         uint32_t &o0, uint32_t &o1){
  uint32_t ks2 = k0 ^ k1 ^ 0x1BD11BDAu;
  x0 += k0; x1 += k1;
  x0+=x1; x1=rotl32(x1,13); x1^=x0;
  x0+=x1; x1=rotl32(x1,15); x1^=x0;
  x0+=x1; x1=rotl32(x1,26); x1^=x0;
  x0+=x1; x1=rotl32(x1,6);  x1^=x0;
  x0+=k1; x1+=ks2+1u;
  x0+=x1; x1=rotl32(x1,17); x1^=x0;
  x0+=x1; x1=rotl32(x1,29); x1^=x0;
  x0+=x1; x1=rotl32(x1,16); x1^=x0;
  x0+=x1; x1=rotl32(x1,24); x1^=x0;
  x0+=ks2; x1+=k0+2u;
  x0+=x1; x1=rotl32(x1,13); x1^=x0;
  x0+=x1; x1=rotl32(x1,15); x1^=x0;
  x0+=x1; x1=rotl32(x1,26); x1^=x0;
  x0+=x1; x1=rotl32(x1,6);  x1^=x0;
  x0+=k0; x1+=k1+3u;
  x0+=x1; x1=rotl32(x1,17); x1^=x0;
  x0+=x1; x1=rotl32(x1,29); x1^=x0;
  x0+=x1; x1=rotl32(x1,16); x1^=x0;
  x0+=x1; x1=rotl32(x1,24); x1^=x0;
  x0+=k1; x1+=ks2+4u;
  x0+=x1; x1=rotl32(x1,13); x1^=x0;
  x0+=x1; x1=rotl32(x1,15); x1^=x0;
  x0+=x1; x1=rotl32(x1,26); x1^=x0;
  x0+=x1; x1=rotl32(x1,6);  x1^=x0;
  x0+=ks2; x1+=k0+5u;
  o0=x0; o1=x1;
}

__device__ __forceinline__ float clip01_div255(float x){
  return fminf(fmaxf(x/255.0f, 0.0f), 1.0f);
}

// ---------- Kernel 1: per-(img,cls) sampling; cls=1 block also does stats ----------
// 64 blocks x 512 threads. Each block computes its own image channel-max (parallel
// duplicate work). tidx exchanged via device-scope atomics; cls1 waits on cls0's
// flag (sentinel != 0xAA poison), then computes mean/std/train_s.
__global__ __launch_bounds__(512) void ksample(const float* __restrict__ in,
                                               int* __restrict__ tidx,
                                               int* __restrict__ flags,
                                               float* __restrict__ train_s,
                                               float* __restrict__ meanstd){
#pragma clang fp contract(off)
  int img = blockIdx.x >> 1;
  int cls = blockIdx.x & 1;     // 0 = fg, 1 = bg
  int tid = threadIdx.x;
  int lane = tid & 63, wv = tid >> 6;

  __shared__ uint32_t score[NPIX];   // 36 KB
  __shared__ uint64_t cand[1024];    // 8 KB
  __shared__ int hist[129];
  __shared__ int ncand, bbin;
  __shared__ float red[3][8];
  __shared__ float feat[100][5];
  __shared__ int   tIdxL[100];
  __shared__ float mv[5], sv[5];

  const float* p = in + (size_t)img*NPIX*3;

  if(tid<129) hist[tid]=0;
  if(tid==0)  ncand=0;

  // ---- channel max (fmax exact & associative; identical result any order)
  float m0=0.f, m1=0.f, m2=0.f;
  for(int i=tid;i<NPIX;i+=512){
    m0=fmaxf(m0, clip01_div255(p[i*3+0]));
    m1=fmaxf(m1, clip01_div255(p[i*3+1]));
    m2=fmaxf(m2, clip01_div255(p[i*3+2]));
  }
  for(int off=32;off>0;off>>=1){
    m0=fmaxf(m0,__shfl_down(m0,off));
    m1=fmaxf(m1,__shfl_down(m1,off));
    m2=fmaxf(m2,__shfl_down(m2,off));
  }
  if(lane==0){ red[0][wv]=m0; red[1][wv]=m1; red[2][wv]=m2; }
  __syncthreads();
  float c0=red[0][0], c1=red[1][0], c2=red[2][0];
  for(int w=1;w<8;w++){
    c0=fmaxf(c0,red[0][w]); c1=fmaxf(c1,red[1][w]); c2=fmaxf(c2,red[2][w]);
  }

  // ---- partitionable threefry keys (bit-exact, verified rounds 1-3)
  uint32_t ik0, ik1; threefry(0u, 42u, 0u, (uint32_t)img, ik0, ik1);
  uint32_t s0, s1;   threefry(ik0, ik1, 0u, (uint32_t)cls, s0, s1);

  // ---- score + histogram
  for(int i=tid;i<NPIX;i+=512){
    float a=clip01_div255(p[i*3+0])/c0;
    float b=clip01_div255(p[i*3+1])/c1;
    float c=clip01_div255(p[i*3+2])/c2;
    bool fg = (a>0.f && a<0.6f) || (b>0.f && b<0.6f) || (c>0.f && c<0.6f);
    bool valid = (cls==0) ? fg : !fg;
    uint32_t b1,b2; threefry(s0, s1, 0u, (uint32_t)i, b1, b2);
    uint32_t vv = valid ? ((b1 ^ b2) >> 9) + 1u : 0u;   // monotone in uniform; 0 = invalid
    score[i] = vv;
    atomicAdd(&hist[vv>>16], 1);
  }
  __syncthreads();

  if(tid==0){
    int acc=0, b=128;
    for(; b>=0; b--){ acc += hist[b]; if(acc>=50) break; }
    bbin = b;
  }
  __syncthreads();

  int bb = bbin;
  for(int i=tid;i<NPIX;i+=512){
    uint32_t vv = score[i];
    if((int)(vv>>16) >= bb){
      int pos = atomicAdd(&ncand,1);
      if(pos < 1024)
        cand[pos] = ((uint64_t)vv << 14) | (uint64_t)(16383 - i);  // higher key = earlier
    }
  }
  __syncthreads();

  int m = ncand; if(m>1024) m=1024;
  for(int c=tid;c<m;c+=512){
    uint64_t k = cand[c];
    int r = 0;
    for(int j=0;j<m;j++) r += (cand[j] > k);
    if(r < 50) atomicExch(&tidx[img*100 + cls*50 + r], 16383 - (int)(k & 16383u));
  }
  __threadfence();
  __syncthreads();
  if(tid==0) atomicExch(&flags[img*2+cls], FLAG_MAGIC);

  if(cls==0) return;

  // ---- cls=1: wait for partner, then stats (bit-identical to round-1/2 kstats)
  if(tid==0){
    while(atomicAdd(&flags[img*2+0],0) != FLAG_MAGIC) { }
  }
  __syncthreads();
  __threadfence();

  if(tid<100) tIdxL[tid] = atomicAdd(&tidx[img*100+tid], 0);
  __syncthreads();
  if(tid<100){
    int pp = tIdxL[tid];
    int i=pp/96, j=pp-i*96;
    const float* px = p + (size_t)pp*3;
    for(int c=0;c<3;c++){
      float ip=clip01_div255(px[c]);
      feat[tid][c]=ip/255.0f;
    }
    feat[tid][3]=((float)i/96.0f)*100.0f;
    feat[tid][4]=((float)j/96.0f)*100.0f;
  }
  __syncthreads();
  if(tid<5){
    float s=0.f;
    for(int r=0;r<100;r++) s=s+feat[r][tid];
    float mu=s/100.0f;
    mv[tid]=mu;
    float v=0.f;
    for(int r=0;r<100;r++){ float d=feat[r][tid]-mu; float q=d*d; v=v+q; }
    sv[tid]=sqrtf(v/100.0f);
  }
  __syncthreads();
  if(tid<100){
    for(int k=0;k<5;k++) train_s[(img*100+tid)*5+k]=(feat[tid][k]-mv[k])/sv[k];
  }
  if(tid<5)       meanstd[img*10+tid]=mv[tid];
  else if(tid<10) meanstd[img*10+tid]=sv[tid-5];
}

// ---------- Kernel 2: brute-force 5-NN, values-only phases + merge-count ----------
__global__ __launch_bounds__(256) void kknn(const float* __restrict__ in,
                                            const float* __restrict__ train_s,
                                            const float* __restrict__ meanstd,
                                            float* __restrict__ out){
#pragma clang fp contract(off)
  int img   = blockIdx.x / 36;
  int chunk = blockIdx.x % 36;
  int tid   = threadIdx.x;
  __shared__ float ts[100][8];       // rows padded to 32B for float4 reads
  __shared__ float mv[5], sv[5];
  __shared__ float pix[768];

  if(tid<100){
    const float* tr = train_s + (img*100+tid)*5;
    ts[tid][0]=tr[0]; ts[tid][1]=tr[1]; ts[tid][2]=tr[2]; ts[tid][3]=tr[3]; ts[tid][4]=tr[4];
  }
  if(tid>=128 && tid<133) mv[tid-128]=meanstd[img*10+(tid-128)];
  if(tid>=160 && tid<165) sv[tid-160]=meanstd[img*10+5+(tid-160)];
  const float* cb = in + ((size_t)img*NPIX + (size_t)chunk*256)*3;
  pix[tid]     = cb[tid];
  pix[tid+256] = cb[tid+256];
  pix[tid+512] = cb[tid+512];
  __syncthreads();

  int p = chunk*256+tid;
  int i=p/96, j=p-i*96;
  float ip0=clip01_div255(pix[tid*3+0]);
  float ip1=clip01_div255(pix[tid*3+1]);
  float ip2=clip01_div255(pix[tid*3+2]);
  float t0,t1,t2,t3,t4;
  {
    float f0=ip0/255.0f, f1=ip1/255.0f, f2=ip2/255.0f;
    float f3=((float)i/96.0f)*100.0f, f4=((float)j/96.0f)*100.0f;
    t0=(f0-mv[0])/sv[0]; t1=(f1-mv[1])/sv[1]; t2=(f2-mv[2])/sv[2];
    t3=(f3-mv[3])/sv[3]; t4=(f4-mv[4])/sv[4];
  }

  // ---- phase A: fg neighbors 0..49, values-only sorted top-5
  float a0=1e30f,a1=1e30f,a2=1e30f,a3=1e30f,a4=1e30f;
#pragma unroll 5
  for(int jn=0;jn<50;jn++){
    float4 q = *(const float4*)&ts[jn][0];
    float  q4 = ts[jn][4];
    float s=0.f;
    { float d=t0-q.x; float w=d*d; s=s+w; }
    { float d=t1-q.y; float w=d*d; s=s+w; }
    { float d=t2-q.z; float w=d*d; s=s+w; }
    { float d=t3-q.w; float w=d*d; s=s+w; }
    { float d=t4-q4;  float w=d*d; s=s+w; }
    float d=sqrtf(s);
    bool l0=d<a0,l1=d<a1,l2=d<a2,l3=d<a3,l4=d<a4;
    a4 = l4 ? (l3?a3:d) : a4;
    a3 = l3 ? (l2?a2:d) : a3;
    a2 = l2 ? (l1?a1:d) : a2;
    a1 = l1 ? (l0?a0:d) : a1;
    a0 = l0 ? d : a0;
  }

  // ---- phase B: bg neighbors 50..99, values-only sorted top-5
  float b0=1e30f,b1=1e30f,b2=1e30f,b3=1e30f,b4=1e30f;
#pragma unroll 5
  for(int jn=50;jn<100;jn++){
    float4 q = *(const float4*)&ts[jn][0];
    float  q4 = ts[jn][4];
    float s=0.f;
    { float d=t0-q.x; float w=d*d; s=s+w; }
    { float d=t1-q.y; float w=d*d; s=s+w; }
    { float d=t2-q.z; float w=d*d; s=s+w; }
    { float d=t3-q.w; float w=d*d; s=s+w; }
    { float d=t4-q4;  float w=d*d; s=s+w; }
    float d=sqrtf(s);
    bool l0=d<b0,l1=d<b1,l2=d<b2,l3=d<b3,l4=d<b4;
    b4 = l4 ? (l3?b3:d) : b4;
    b3 = l3 ? (l2?b2:d) : b3;
    b2 = l2 ? (l1?b1:d) : b2;
    b1 = l1 ? (l0?b0:d) : b1;
    b0 = l0 ? d : b0;
  }

  // ---- merge-count: fg in joint top-5. fg (idx<50) wins ties vs bg.
  // fa[i] in top5  <=>  #{bg strictly closer} <= 4-i  <=>  fa[i] <= fb[4-i]
  int cnt = (a0<=b4)+(a1<=b3)+(a2<=b2)+(a3<=b1)+(a4<=b0);
  bool seg = cnt>=2;                  // mean>=0.3  <=>  count>=2
  __syncthreads();                    // pix[] reuse fence
  pix[tid*3+0]=seg?ip0:0.f;
  pix[tid*3+1]=seg?ip1:0.f;
  pix[tid*3+2]=seg?ip2:0.f;
  __syncthreads();
  float* ob = out + ((size_t)img*NPIX + (size_t)chunk*256)*3;
  ob[tid]     = pix[tid];
  ob[tid+256] = pix[tid+256];
  ob[tid+512] = pix[tid+512];
}

extern "C" void kernel_launch(void* const* d_in, const int* in_sizes, int n_in,
                              void* d_out, int out_size, void* d_ws, size_t ws_size,
                              hipStream_t stream) {
  const float* in = (const float*)d_in[0];
  float* out = (float*)d_out;
  int*   tidx    = (int*)d_ws;                          // 32*100*4 = 12800 B
  int*   flags   = (int*)((char*)d_ws + 12800);         // 64*4 = 256 B   (0xAA poison != MAGIC)
  float* train_s = (float*)((char*)d_ws + 13056);       // 32*500*4 = 64000 B
  float* meanstd = (float*)((char*)d_ws + 77056);       // 32*10*4  = 1280 B

  ksample<<<NIMG*2,  512, 0, stream>>>(in, tidx, flags, train_s, meanstd);
  kknn   <<<NIMG*36, 256, 0, stream>>>(in, train_s, meanstd, out);
}